// Round 10
// baseline (204.432 us; speedup 1.0000x reference)
//
#include <hip/hip_runtime.h>
#include <math.h>

// Problem constants
#define T_  204
#define I_  5
#define H_  24
#define L_  10
#define O_  612
#define Bsz 8192

typedef _Float16 half8 __attribute__((ext_vector_type(8)));
typedef _Float16 half2t __attribute__((ext_vector_type(2)));
typedef float    float4t __attribute__((ext_vector_type(4)));

union U16B { float4t f4; half8 h8; float f[4]; _Float16 h[8]; half2t h2[4]; };

__device__ __forceinline__ float fast_rcp(float x){ return __builtin_amdgcn_rcpf(x); }
__device__ __forceinline__ float fast_ex2(float x){ return __builtin_amdgcn_exp2f(x); }
__device__ __forceinline__ half2t pk2(float a, float b){
    return __builtin_bit_cast(half2t, __builtin_amdgcn_cvt_pkrtz(a, b));
}
// lane <-> lane^8 within each 16-lane row: v_mov_dpp row_ror:8 (full-rate VALU,
// no LDS pipe, no lgkmcnt). ror by 8 on 16 lanes is symmetric (== xor 8).
__device__ __forceinline__ float dpp_xor8(float v){
    const int r = __builtin_amdgcn_mov_dpp(__builtin_bit_cast(int, v),
                                           0x128 /*row_ror:8*/, 0xf, 0xf, true);
    return __builtin_bit_cast(float, r);
}

#define MFMA16(a,b,c) __builtin_amdgcn_mfma_f32_16x16x32_f16((a),(b),(c),0,0,0)

#define L2E  1.44269504f
#define L2E2 2.88539008f

// Prepack fc0_w into per-timestep fp16 A-fragments (A[m=l][k=j], zeros elsewhere).
__global__ __launch_bounds__(64)
void pack_fc0(const float* __restrict__ fc0_w, float4t* __restrict__ dst)
{
    const int t = blockIdx.x, lane = threadIdx.x;
    const int m = lane & 15, q = lane >> 4;
    U16B v;
    #pragma unroll
    for (int i = 0; i < 8; ++i) {
        const int k = 8*q + i;
        float f = (m < L_ && k < H_) ? fc0_w[m*(T_*H_) + t*H_ + k] : 0.0f;
        v.h[i] = (_Float16)f;
    }
    dst[t*64 + lane] = v.f4;
}

// R15 fused-denominator activation, per unit (bitwise-identical results)
#define ACT1(Dv, cc, hh)                                                        \
  {                                                                             \
    const float ei = fast_ex2((Dv)[0] * -L2E);                                  \
    const float ef = fast_ex2((Dv)[1] * -L2E);                                  \
    const float eg = fast_ex2((Dv)[2] *  L2E2);                                 \
    const float eo = fast_ex2((Dv)[3] * -L2E);                                  \
    const float Dn1 = 1.f + ef;                                                 \
    const float Dn2 = 1.f + ei;                                                 \
    const float Dn3 = eg + 1.f;                                                 \
    const float G   = eg - 1.f;                                                 \
    const float P   = Dn2 * Dn3;                                                \
    const float R1  = fast_rcp(Dn1 * P);                                        \
    const float nm  = fmaf((cc), P, Dn1 * G);                                   \
    (cc) = nm * R1;                                                             \
    const float es  = fast_ex2(__builtin_fabsf(cc) * -L2E2);                    \
    const float R2  = fast_rcp((1.f + eo) * (1.f + es));                        \
    (hh) = __builtin_copysignf((1.f - es) * R2, (cc));                          \
  }

// R21: all-rounds fit: wall = F(~1030cy latency floor) + per-wave issue(~485);
// shared-lgkmcnt explains why SW chain-interleave failed (R12) while HW waves
// fill F (R16). Only lever left is F; removable component = the ds_bpermute
// round trip + lgkmcnt(0) on the h->B critical path. This version: 8 straight
// gate tiles of 3 units (A rows 12-15 zero) at batch-8 dup, so lane (q<3,m)
// owns units 8q+{0..3} (lo) or 8q+{4..7} (hi) -> 4 ACT1/lane, and the ONLY
// exchange is lane^8 = DPP row_ror:8 (VALU, no DS). q3 lanes act on zero-gates
// (junk, harmless) and build the x-frag as before. Every A/D/h value and pk2
// pairing identical to R20 -> bitwise-identical output. Ring-4 prefetch kept.
#define POS(K, faK, xsK)                                                        \
  {                                                                             \
    float4t D0 = MFMA16(Ag[0], B.h8, zf4);                                      \
    float4t D1 = MFMA16(Ag[1], B.h8, zf4);                                      \
    float4t D2 = MFMA16(Ag[2], B.h8, zf4);                                      \
    float4t D3 = MFMA16(Ag[3], B.h8, zf4);                                      \
    float4t D4 = MFMA16(Ag[4], B.h8, zf4);                                      \
    float4t D5 = MFMA16(Ag[5], B.h8, zf4);                                      \
    float4t D6 = MFMA16(Ag[6], B.h8, zf4);                                      \
    float4t D7 = MFMA16(Ag[7], B.h8, zf4);                                      \
    const float4t E0 = mhi ? D4 : D0;                                           \
    const float4t E1 = mhi ? D5 : D1;                                           \
    const float4t E2 = mhi ? D6 : D2;                                           \
    const float4t E3 = mhi ? D7 : D3;                                           \
    float h0, h1, h2, h3;                                                       \
    ACT1(E0, c0, h0)                                                            \
    ACT1(E1, c1, h1)                                                            \
    ACT1(E2, c2, h2)                                                            \
    ACT1(E3, c3, h3)                                                            \
    /* own pair-packs; partner (lane^8) has the other 4 units, same batch */    \
    const float pA = __builtin_bit_cast(float, pk2(h0, h1));                    \
    const float pB = __builtin_bit_cast(float, pk2(h2, h3));                    \
    const float rA = dpp_xor8(pA);                                              \
    const float rB = dpp_xor8(pB);                                              \
    if (q < 3) {                                                                \
      /* lo lane: units 8q+0..3 own, 4..7 from partner; hi lane: swapped */     \
      B.h2[0] = __builtin_bit_cast(half2t, mhi ? rA : pA);                      \
      B.h2[1] = __builtin_bit_cast(half2t, mhi ? rB : pB);                      \
      B.h2[2] = __builtin_bit_cast(half2t, mhi ? pA : rA);                      \
      B.h2[3] = __builtin_bit_cast(half2t, mhi ? pB : rB);                      \
    } else {                                                                    \
      B.h2[0] = pk2(xsK[0], xsK[1]);                                            \
      B.h2[1] = pk2(xsK[2], xsK[3]);                                            \
      B.h2[2] = pk2(xsK[4], 1.0f);                                              \
      B.h2[3] = pk2(0.f, 0.f);                                                  \
    }                                                                           \
    { U16B fF; fF.f4 = faK;                                                     \
      accF = MFMA16(fF.h8, B.h8, accF); }                                       \
    /* slot reloads: consumed again at step t+K+4 (4-step vmcnt shadow) */      \
    { const int tf = (t + K + 4 < T_) ? t + K + 4 : T_ - 1;                     \
      faK = fc0A[tf*64 + lane]; }                                               \
    if (q == 3) {                                                               \
      const int txi = (t + K + 5 < T_) ? t + K + 5 : T_ - 1;                    \
      const float* xq = xp + txi*I_;                                            \
      _Pragma("unroll")                                                         \
      for (int i = 0; i < I_; ++i) xsK[i] = xq[i];                              \
    }                                                                           \
  }

__global__ __launch_bounds__(64, 1)
void lstm_mfma(const float* __restrict__ x,
               const float* __restrict__ W_ih,
               const float* __restrict__ W_hh,
               const float* __restrict__ b_ih,
               const float* __restrict__ b_hh,
               const float* __restrict__ fc0_b,
               const float* __restrict__ out_w,
               const float* __restrict__ out_b,
               const float4t* __restrict__ fc0A,   // prepacked in d_ws
               float* __restrict__ out)
{
    __shared__ __align__(16) _Float16 actL[16*24];  // epilogue staging only

    const int lane = threadIdx.x;
    const int m = lane & 15;         // B col (batch, cols 8-15 duplicate 0-7)
    const int q = lane >> 4;         // quad
    const int mb = m & 7;            // batch sub-index
    const bool mhi = (m >= 8);       // upper half: owns units 8q+4..7
    const int eb = blockIdx.x * 8 + mb;   // batch element

    const float4t zf4 = {0.f, 0.f, 0.f, 0.f};

    // ---- gate A-fragments: 8 straight tiles of 3 units (rows 12-15 zero) ----
    // Tile T row mm (mm<12): gate (mm&3) of unit 8*(mm>>2)+T.
    // => lane (q<3,m) D reg r of tile T = gate r of unit 8q+T (own B-slot!).
    half8 Ag[8];
    #pragma unroll
    for (int T8 = 0; T8 < 8; ++T8) {
        U16B tw;
        if (m < 12) {
            const int u = 8*(m >> 2) + T8;
            const int srow = (m & 3) * H_ + u;       // torch gate-major row
            float wv[8];
            if (q < 3) {
                const float4t* pw = (const float4t*)(W_hh + srow*H_ + 8*q);
                float4t wa = pw[0], wb = pw[1];
                #pragma unroll
                for (int i = 0; i < 4; ++i) { wv[i] = wa[i]; wv[4+i] = wb[i]; }
            } else {
                #pragma unroll
                for (int i = 0; i < 8; ++i) wv[i] = 0.f;
                #pragma unroll
                for (int i = 0; i < I_; ++i) wv[i] = W_ih[srow*I_ + i];
                wv[5] = b_ih[srow] + b_hh[srow];
            }
            #pragma unroll
            for (int i = 0; i < 8; ++i) tw.h[i] = (_Float16)wv[i];
        } else {
            tw.f4 = zf4;
        }
        Ag[T8] = tw.h8;
    }

    const float* xp = x + (size_t)eb * (T_*I_);

    // ---- initial B-frag [h=0 | x_0 | 1 | 0,0] ----
    U16B B;
    if (q == 3) {
        B.h2[0] = pk2(xp[0], xp[1]);
        B.h2[1] = pk2(xp[2], xp[3]);
        B.h2[2] = pk2(xp[4], 1.0f);
        B.h2[3] = pk2(0.f, 0.f);
    } else {
        B.f4 = zf4;
    }

    // ---- depth-4 prefetch ring, named slots ----
    float4t fa0 = fc0A[0*64 + lane];
    float4t fa1 = fc0A[1*64 + lane];
    float4t fa2 = fc0A[2*64 + lane];
    float4t fa3 = fc0A[3*64 + lane];
    float xs0[I_] = {0,0,0,0,0}, xs1[I_] = {0,0,0,0,0};
    float xs2[I_] = {0,0,0,0,0}, xs3[I_] = {0,0,0,0,0};
    if (q == 3) {
        #pragma unroll
        for (int i = 0; i < I_; ++i) {
            xs0[i] = xp[1*I_ + i];   // x(1) consumed at t=0
            xs1[i] = xp[2*I_ + i];
            xs2[i] = xp[3*I_ + i];
            xs3[i] = xp[4*I_ + i];
        }
    }

    // 4 cell states per lane: units 8q + (mhi?4:0) + {0,1,2,3}, batch mb
    // (q3 lanes: zero-gate junk states, never consumed)
    float c0 = 0.f, c1 = 0.f, c2 = 0.f, c3 = 0.f;
    float4t accF = zf4;

    // ================= time loop: 51 x 4 steps, copy-free ring =============
    #pragma unroll 1
    for (int t = 0; t < T_; t += 4) {
        POS(0, fa0, xs0)
        POS(1, fa1, xs1)
        POS(2, fa2, xs2)
        POS(3, fa3, xs3)
    }

    // ================= epilogue (R7/R8 structure; stores m<8 only) =========
    float av[4];
    #pragma unroll
    for (int r = 0; r < 4; ++r) {
        const int l = 4*q + r;
        const float fb = (l < L_) ? fc0_b[l] : 0.f;
        const float v = accF[r] + fb;
        av[r] = (l < L_) ? fmaxf(v, 0.f) : 0.f;
    }
    *(half2t*)(&actL[m*24 + 4*q])     = pk2(av[0], av[1]);
    *(half2t*)(&actL[m*24 + 4*q + 2]) = pk2(av[2], av[3]);
    __builtin_amdgcn_wave_barrier();

    U16B Ba;
    if (q < 2) Ba.f4 = *(const float4t*)(&actL[m*24 + q*8]);
    else       Ba.f4 = zf4;            // k>=16 unused (out_w A-frag zero there)

    for (int Tt = 0; Tt < 39; ++Tt) {
        const int row = 16*Tt + m;
        float w0=0.f,w1=0.f,w2=0.f,w3=0.f,w4=0.f,w5=0.f,w6=0.f,w7=0.f;
        if (row < O_ && q < 2) {
            const float2* p2 = (const float2*)(out_w + row*L_);
            if (q == 0) {
                float2 a = p2[0], b = p2[1], cc = p2[2], dd = p2[3];
                w0=a.x; w1=a.y; w2=b.x; w3=b.y; w4=cc.x; w5=cc.y; w6=dd.x; w7=dd.y;
            } else {
                float2 a = p2[4];
                w0=a.x; w1=a.y;
            }
        }
        U16B Aw;
        Aw.h2[0] = pk2(w0,w1); Aw.h2[1] = pk2(w2,w3);
        Aw.h2[2] = pk2(w4,w5); Aw.h2[3] = pk2(w6,w7);

        float4t dd = MFMA16(Aw.h8, Ba.h8, zf4);

        const int ob = 16*Tt + 4*q;
        if (ob < O_ && m < 8) {
            const float4t bias = *(const float4t*)(out_b + ob);
            #pragma unroll
            for (int r = 0; r < 4; ++r) dd[r] += bias[r];
            *(float4t*)(out + (size_t)eb*O_ + ob) = dd;
        }
    }
}

extern "C" void kernel_launch(void* const* d_in, const int* in_sizes, int n_in,
                              void* d_out, int out_size, void* d_ws, size_t ws_size,
                              hipStream_t stream)
{
    const float* x     = (const float*)d_in[0];
    const float* W_ih  = (const float*)d_in[1];
    const float* W_hh  = (const float*)d_in[2];
    const float* b_ih  = (const float*)d_in[3];
    const float* b_hh  = (const float*)d_in[4];
    const float* fc0_w = (const float*)d_in[5];
    const float* fc0_b = (const float*)d_in[6];
    const float* out_w = (const float*)d_in[7];
    const float* out_b = (const float*)d_in[8];
    float* out = (float*)d_out;
    (void)ws_size;

    pack_fc0<<<dim3(T_), dim3(64), 0, stream>>>(fc0_w, (float4t*)d_ws);
    lstm_mfma<<<dim3(Bsz/8), dim3(64), 0, stream>>>(
        x, W_ih, W_hh, b_ih, b_hh, fc0_b, out_w, out_b,
        (const float4t*)d_ws, out);
}

// Round 11
// 194.198 us; speedup vs baseline: 1.0527x; 1.0527x over previous
//
#include <hip/hip_runtime.h>
#include <math.h>

// Problem constants
#define T_  204
#define I_  5
#define H_  24
#define L_  10
#define O_  612
#define Bsz 8192

typedef _Float16 half8 __attribute__((ext_vector_type(8)));
typedef _Float16 half2t __attribute__((ext_vector_type(2)));
typedef float    float4t __attribute__((ext_vector_type(4)));

union U16B { float4t f4; half8 h8; float f[4]; _Float16 h[8]; half2t h2[4]; };

__device__ __forceinline__ float fast_rcp(float x){ return __builtin_amdgcn_rcpf(x); }
__device__ __forceinline__ float fast_ex2(float x){ return __builtin_amdgcn_exp2f(x); }
__device__ __forceinline__ half2t pk2(float a, float b){
    return __builtin_bit_cast(half2t, __builtin_amdgcn_cvt_pkrtz(a, b));
}
// lane <-> lane^8 within each 16-lane row: v_mov_dpp row_ror:8 (VALU pipe,
// no lgkmcnt; bit-exact equivalence to __shfl(lane^8) proven in R21).
__device__ __forceinline__ float dpp_xor8(float v){
    const int r = __builtin_amdgcn_mov_dpp(__builtin_bit_cast(int, v),
                                           0x128 /*row_ror:8*/, 0xf, 0xf, true);
    return __builtin_bit_cast(float, r);
}

#define MFMA16(a,b,c) __builtin_amdgcn_mfma_f32_16x16x32_f16((a),(b),(c),0,0,0)

#define L2E  1.44269504f
#define L2E2 2.88539008f

// Unit owned by lane-quad q, tile T (q<3: 8q+T; q==3: overflow units 6,7,14,15,22,23)
__device__ __forceinline__ int unit_of(int q, int T) {
    return (q < 3) ? (8*q + T) : (8*(T >> 1) + 6 + (T & 1));
}

// Prepack fc0_w into per-timestep fp16 A-fragments (A[m=l][k=j], zeros elsewhere).
__global__ __launch_bounds__(64)
void pack_fc0(const float* __restrict__ fc0_w, float4t* __restrict__ dst)
{
    const int t = blockIdx.x, lane = threadIdx.x;
    const int m = lane & 15, q = lane >> 4;
    U16B v;
    #pragma unroll
    for (int i = 0; i < 8; ++i) {
        const int k = 8*q + i;
        float f = (m < L_ && k < H_) ? fc0_w[m*(T_*H_) + t*H_ + k] : 0.0f;
        v.h[i] = (_Float16)f;
    }
    dst[t*64 + lane] = v.f4;
}

// R22: final model: wall = (per-wave issue) + S, S = per-SIMD stall tax shared
// by co-resident waves (R16). (w=1,b=8) = R20 is the optimum of the w*b=8
// family (fixed-I dominates). Residual S ~600cy includes ~300-400cy of the
// three act chains' rcp->exp->rcp TAILS exposed serially (depth-first
// clustering). R15 tested breadth-first at the wrong structure; R19 tested it
// WITH barriers (which killed cross-step overlap). This round: breadth-first
// tails as named scalars, NO barriers, on the R20 winner + DPP partner
// exchange (3 fewer bpermutes). Values identical -> absmax 0.001953125.
#define POS(K, faK, xsK)                                                        \
  {                                                                             \
    float4t D0 = MFMA16(Ag[0], B.h8, zf4);                                      \
    float4t D1 = MFMA16(Ag[1], B.h8, zf4);                                      \
    float4t D2 = MFMA16(Ag[2], B.h8, zf4);                                      \
    float4t D3 = MFMA16(Ag[3], B.h8, zf4);                                      \
    float4t D4 = MFMA16(Ag[4], B.h8, zf4);                                      \
    float4t D5 = MFMA16(Ag[5], B.h8, zf4);                                      \
    const float4t E0 = mhi ? D3 : D0;                                           \
    const float4t E1 = mhi ? D4 : D1;                                           \
    const float4t E2 = mhi ? D5 : D2;                                           \
    /* ---- breadth-first act: phase 1 = all 12 exps ---- */                    \
    const float ei0 = fast_ex2(E0[0] * -L2E);                                   \
    const float ei1 = fast_ex2(E1[0] * -L2E);                                   \
    const float ei2 = fast_ex2(E2[0] * -L2E);                                   \
    const float ef0 = fast_ex2(E0[1] * -L2E);                                   \
    const float ef1 = fast_ex2(E1[1] * -L2E);                                   \
    const float ef2 = fast_ex2(E2[1] * -L2E);                                   \
    const float eg0 = fast_ex2(E0[2] *  L2E2);                                  \
    const float eg1 = fast_ex2(E1[2] *  L2E2);                                  \
    const float eg2 = fast_ex2(E2[2] *  L2E2);                                  \
    const float eo0 = fast_ex2(E0[3] * -L2E);                                   \
    const float eo1 = fast_ex2(E1[3] * -L2E);                                   \
    const float eo2 = fast_ex2(E2[3] * -L2E);                                   \
    /* ---- phase 2: denominators + R1 rcps + numerators, interleaved ---- */   \
    const float Dn0 = 1.f + ef0;                                                \
    const float Dn1 = 1.f + ef1;                                                \
    const float Dn2 = 1.f + ef2;                                                \
    const float Pp0 = (1.f + ei0) * (eg0 + 1.f);                                \
    const float Pp1 = (1.f + ei1) * (eg1 + 1.f);                                \
    const float Pp2 = (1.f + ei2) * (eg2 + 1.f);                                \
    const float R10 = fast_rcp(Dn0 * Pp0);                                      \
    const float R11 = fast_rcp(Dn1 * Pp1);                                      \
    const float R12 = fast_rcp(Dn2 * Pp2);                                      \
    const float nm0 = fmaf(c0, Pp0, Dn0 * (eg0 - 1.f));                         \
    const float nm1 = fmaf(c1, Pp1, Dn1 * (eg1 - 1.f));                         \
    const float nm2 = fmaf(c2, Pp2, Dn2 * (eg2 - 1.f));                         \
    /* ---- phase 3: c' updates + es exps, interleaved ---- */                  \
    c0 = nm0 * R10;                                                             \
    c1 = nm1 * R11;                                                             \
    c2 = nm2 * R12;                                                             \
    const float es0 = fast_ex2(__builtin_fabsf(c0) * -L2E2);                    \
    const float es1 = fast_ex2(__builtin_fabsf(c1) * -L2E2);                    \
    const float es2 = fast_ex2(__builtin_fabsf(c2) * -L2E2);                    \
    /* ---- phase 4: R2 rcps + h, interleaved ---- */                           \
    const float R20_ = fast_rcp((1.f + eo0) * (1.f + es0));                     \
    const float R21_ = fast_rcp((1.f + eo1) * (1.f + es1));                     \
    const float R22_ = fast_rcp((1.f + eo2) * (1.f + es2));                     \
    const float h0 = __builtin_copysignf((1.f - es0) * R20_, c0);               \
    const float h1 = __builtin_copysignf((1.f - es1) * R21_, c1);               \
    const float h2 = __builtin_copysignf((1.f - es2) * R22_, c2);               \
    /* partner (lane^8) exchange via DPP (VALU); q3 pulls via bpermute */       \
    const float s0 = dpp_xor8(h0);                                              \
    const float s1 = dpp_xor8(h1);                                              \
    const float s2 = dpp_xor8(h2);                                              \
    const float rA = __shfl(h0, srcA, 64);                                      \
    const float rB = __shfl(h1, srcB, 64);                                      \
    const float rC = __shfl(h2, srcC, 64);                                      \
    if (q < 3) {                                                                \
      B.h2[0] = pk2(mhi ? s0 : h0, mhi ? s1 : h1);                              \
      B.h2[1] = pk2(mhi ? s2 : h2, mhi ? h0 : s0);                              \
      B.h2[2] = pk2(mhi ? h1 : s1, mhi ? h2 : s2);                              \
      const float pa = (q == 0) ? rA : ((q == 1) ? rC : rB);                    \
      const float pb = (q == 0) ? rB : ((q == 1) ? rA : rC);                    \
      B.h2[3] = pk2(pa, pb);                                                    \
    } else {                                                                    \
      B.h2[0] = pk2(xsK[0], xsK[1]);                                            \
      B.h2[1] = pk2(xsK[2], xsK[3]);                                            \
      B.h2[2] = pk2(xsK[4], 1.0f);                                              \
      B.h2[3] = pk2(0.f, 0.f);                                                  \
    }                                                                           \
    { U16B fF; fF.f4 = faK;                                                     \
      accF = MFMA16(fF.h8, B.h8, accF); }                                       \
    /* slot reloads: consumed again at step t+K+4 (4-step vmcnt shadow) */      \
    { const int tf = (t + K + 4 < T_) ? t + K + 4 : T_ - 1;                     \
      faK = fc0A[tf*64 + lane]; }                                               \
    if (q == 3) {                                                               \
      const int txi = (t + K + 5 < T_) ? t + K + 5 : T_ - 1;                    \
      const float* xq = xp + txi*I_;                                            \
      _Pragma("unroll")                                                         \
      for (int i = 0; i < I_; ++i) xsK[i] = xq[i];                              \
    }                                                                           \
  }

__global__ __launch_bounds__(64)
void lstm_mfma(const float* __restrict__ x,
               const float* __restrict__ W_ih,
               const float* __restrict__ W_hh,
               const float* __restrict__ b_ih,
               const float* __restrict__ b_hh,
               const float* __restrict__ fc0_b,
               const float* __restrict__ out_w,
               const float* __restrict__ out_b,
               const float4t* __restrict__ fc0A,   // prepacked in d_ws
               float* __restrict__ out)
{
    __shared__ __align__(16) _Float16 actL[16*24];  // epilogue staging only

    const int lane = threadIdx.x;
    const int m = lane & 15;         // B col (batch, cols 8-15 duplicate 0-7)
    const int q = lane >> 4;         // quad
    const int mb = m & 7;            // batch sub-index
    const bool mhi = (m >= 8);       // upper half: owns unit tiles 3-5
    const int eb = blockIdx.x * 8 + mb;   // batch element

    // q3-pull source lanes (per-lane constants; see R20 derivation)
    const int srcA = ((q == 1) ? 56 : 48) + mb;
    const int srcB = ((q == 2) ? 56 : 48) + mb;
    const int srcC = ((q == 2) ? 56 : 48) + mb;

    const float4t zf4 = {0.f, 0.f, 0.f, 0.f};

    // ---- gate A-fragments (identical to R20) ----
    half8 Ag[6];
    #pragma unroll
    for (int T6 = 0; T6 < 6; ++T6) {
        const int u = unit_of(m >> 2, T6);
        const int srow = (m & 3) * H_ + u;       // torch gate-major row
        float wv[8];
        if (q < 3) {
            const float4t* pw = (const float4t*)(W_hh + srow*H_ + 8*q);
            float4t wa = pw[0], wb = pw[1];
            #pragma unroll
            for (int i = 0; i < 4; ++i) { wv[i] = wa[i]; wv[4+i] = wb[i]; }
        } else {
            #pragma unroll
            for (int i = 0; i < 8; ++i) wv[i] = 0.f;
            #pragma unroll
            for (int i = 0; i < I_; ++i) wv[i] = W_ih[srow*I_ + i];
            wv[5] = b_ih[srow] + b_hh[srow];
        }
        U16B tw;
        #pragma unroll
        for (int i = 0; i < 8; ++i) tw.h[i] = (_Float16)wv[i];
        Ag[T6] = tw.h8;
    }

    const float* xp = x + (size_t)eb * (T_*I_);

    // ---- initial B-frag [h=0 | x_0 | 1 | 0,0] ----
    U16B B;
    if (q == 3) {
        B.h2[0] = pk2(xp[0], xp[1]);
        B.h2[1] = pk2(xp[2], xp[3]);
        B.h2[2] = pk2(xp[4], 1.0f);
        B.h2[3] = pk2(0.f, 0.f);
    } else {
        B.f4 = zf4;
    }

    // ---- depth-4 prefetch ring, named slots ----
    float4t fa0 = fc0A[0*64 + lane];
    float4t fa1 = fc0A[1*64 + lane];
    float4t fa2 = fc0A[2*64 + lane];
    float4t fa3 = fc0A[3*64 + lane];
    float xs0[I_] = {0,0,0,0,0}, xs1[I_] = {0,0,0,0,0};
    float xs2[I_] = {0,0,0,0,0}, xs3[I_] = {0,0,0,0,0};
    if (q == 3) {
        #pragma unroll
        for (int i = 0; i < I_; ++i) {
            xs0[i] = xp[1*I_ + i];   // x(1) consumed at t=0
            xs1[i] = xp[2*I_ + i];
            xs2[i] = xp[3*I_ + i];
            xs3[i] = xp[4*I_ + i];
        }
    }

    // 3 cell states per lane: units unit_of(q, (mhi?3:0)+j), batch mb
    float c0 = 0.f, c1 = 0.f, c2 = 0.f;
    float4t accF = zf4;

    // ================= time loop: 51 x 4 steps, copy-free ring =============
    #pragma unroll 1
    for (int t = 0; t < T_; t += 4) {
        POS(0, fa0, xs0)
        POS(1, fa1, xs1)
        POS(2, fa2, xs2)
        POS(3, fa3, xs3)
    }

    // ================= epilogue (R7/R8 structure; stores m<8 only) =========
    float av[4];
    #pragma unroll
    for (int r = 0; r < 4; ++r) {
        const int l = 4*q + r;
        const float fb = (l < L_) ? fc0_b[l] : 0.f;
        const float v = accF[r] + fb;
        av[r] = (l < L_) ? fmaxf(v, 0.f) : 0.f;
    }
    *(half2t*)(&actL[m*24 + 4*q])     = pk2(av[0], av[1]);
    *(half2t*)(&actL[m*24 + 4*q + 2]) = pk2(av[2], av[3]);
    __builtin_amdgcn_wave_barrier();

    U16B Ba;
    if (q < 2) Ba.f4 = *(const float4t*)(&actL[m*24 + q*8]);
    else       Ba.f4 = zf4;            // k>=16 unused (out_w A-frag zero there)

    for (int Tt = 0; Tt < 39; ++Tt) {
        const int row = 16*Tt + m;
        float w0=0.f,w1=0.f,w2=0.f,w3=0.f,w4=0.f,w5=0.f,w6=0.f,w7=0.f;
        if (row < O_ && q < 2) {
            const float2* p2 = (const float2*)(out_w + row*L_);
            if (q == 0) {
                float2 a = p2[0], b = p2[1], cc = p2[2], dd = p2[3];
                w0=a.x; w1=a.y; w2=b.x; w3=b.y; w4=cc.x; w5=cc.y; w6=dd.x; w7=dd.y;
            } else {
                float2 a = p2[4];
                w0=a.x; w1=a.y;
            }
        }
        U16B Aw;
        Aw.h2[0] = pk2(w0,w1); Aw.h2[1] = pk2(w2,w3);
        Aw.h2[2] = pk2(w4,w5); Aw.h2[3] = pk2(w6,w7);

        float4t dd = MFMA16(Aw.h8, Ba.h8, zf4);

        const int ob = 16*Tt + 4*q;
        if (ob < O_ && m < 8) {
            const float4t bias = *(const float4t*)(out_b + ob);
            #pragma unroll
            for (int r = 0; r < 4; ++r) dd[r] += bias[r];
            *(float4t*)(out + (size_t)eb*O_ + ob) = dd;
        }
    }
}

extern "C" void kernel_launch(void* const* d_in, const int* in_sizes, int n_in,
                              void* d_out, int out_size, void* d_ws, size_t ws_size,
                              hipStream_t stream)
{
    const float* x     = (const float*)d_in[0];
    const float* W_ih  = (const float*)d_in[1];
    const float* W_hh  = (const float*)d_in[2];
    const float* b_ih  = (const float*)d_in[3];
    const float* b_hh  = (const float*)d_in[4];
    const float* fc0_w = (const float*)d_in[5];
    const float* fc0_b = (const float*)d_in[6];
    const float* out_w = (const float*)d_in[7];
    const float* out_b = (const float*)d_in[8];
    float* out = (float*)d_out;
    (void)ws_size;

    pack_fc0<<<dim3(T_), dim3(64), 0, stream>>>(fc0_w, (float4t*)d_ws);
    lstm_mfma<<<dim3(Bsz/8), dim3(64), 0, stream>>>(
        x, W_ih, W_hh, b_ih, b_hh, fc0_b, out_w, out_b,
        (const float4t*)d_ws, out);
}

// Round 12
// 190.907 us; speedup vs baseline: 1.0708x; 1.0172x over previous
//
#include <hip/hip_runtime.h>
#include <math.h>

// Problem constants
#define T_  204
#define I_  5
#define H_  24
#define L_  10
#define O_  612
#define Bsz 8192

typedef _Float16 half8 __attribute__((ext_vector_type(8)));
typedef _Float16 half2t __attribute__((ext_vector_type(2)));
typedef float    float4t __attribute__((ext_vector_type(4)));

union U16B { float4t f4; half8 h8; float f[4]; _Float16 h[8]; half2t h2[4]; };

__device__ __forceinline__ float fast_rcp(float x){ return __builtin_amdgcn_rcpf(x); }
__device__ __forceinline__ float fast_ex2(float x){ return __builtin_amdgcn_exp2f(x); }
__device__ __forceinline__ half2t pk2(float a, float b){
    return __builtin_bit_cast(half2t, __builtin_amdgcn_cvt_pkrtz(a, b));
}
// lane <-> lane^8 within each 16-lane row: v_mov_dpp row_ror:8 (VALU pipe,
// no lgkmcnt; bit-exact equivalence to __shfl(lane^8) proven in R21).
__device__ __forceinline__ float dpp_xor8(float v){
    const int r = __builtin_amdgcn_mov_dpp(__builtin_bit_cast(int, v),
                                           0x128 /*row_ror:8*/, 0xf, 0xf, true);
    return __builtin_bit_cast(float, r);
}

#define MFMA16(a,b,c) __builtin_amdgcn_mfma_f32_16x16x32_f16((a),(b),(c),0,0,0)

#define L2E  1.44269504f
#define L2E2 2.88539008f

// Unit owned by lane-quad q, tile T (q<3: 8q+T; q==3: overflow units 6,7,14,15,22,23)
__device__ __forceinline__ int unit_of(int q, int T) {
    return (q < 3) ? (8*q + T) : (8*(T >> 1) + 6 + (T & 1));
}

// Prepack fc0_w into per-timestep fp16 A-fragments (A[m=l][k=j], zeros elsewhere).
__global__ __launch_bounds__(64)
void pack_fc0(const float* __restrict__ fc0_w, float4t* __restrict__ dst)
{
    const int t = blockIdx.x, lane = threadIdx.x;
    const int m = lane & 15, q = lane >> 4;
    U16B v;
    #pragma unroll
    for (int i = 0; i < 8; ++i) {
        const int k = 8*q + i;
        float f = (m < L_ && k < H_) ? fc0_w[m*(T_*H_) + t*H_ + k] : 0.0f;
        v.h[i] = (_Float16)f;
    }
    dst[t*64 + lane] = v.f4;
}

// R23: R22 budget: busy ~750 cy/step (trans-issue 336 the biggest bucket),
// stall ~600 (chain latency, unfillable at the hard 1-wave/SIMD cap). All
// macro-levers measured (R12-R22); this round slims issue, value-identical:
// (1) clamp-free fa reloads: main loop to t=196 (reloads reach step 203
//     exactly), fap pointer + literal imm offsets, one bump per 4 steps;
//     final 4 steps peeled with no reloads.
// (2) 2-shfl exchange: q3 pre-packs overflow pairs (Xa = lo:(u6,u7)/
//     hi:(u22,u23); Xb = (u14,u15) via the existing s0 dpp); consumers pull
//     one packed float. Same cvt_pkrtz inputs -> same f16 bits.
// absmax stays exactly 0.001953125.

// core step: MFMAs + breadth-first act + exchange + B rebuild + fc0 acc
#define POSC(faK, xsK)                                                          \
  {                                                                             \
    float4t D0 = MFMA16(Ag[0], B.h8, zf4);                                      \
    float4t D1 = MFMA16(Ag[1], B.h8, zf4);                                      \
    float4t D2 = MFMA16(Ag[2], B.h8, zf4);                                      \
    float4t D3 = MFMA16(Ag[3], B.h8, zf4);                                      \
    float4t D4 = MFMA16(Ag[4], B.h8, zf4);                                      \
    float4t D5 = MFMA16(Ag[5], B.h8, zf4);                                      \
    const float4t E0 = mhi ? D3 : D0;                                           \
    const float4t E1 = mhi ? D4 : D1;                                           \
    const float4t E2 = mhi ? D5 : D2;                                           \
    /* ---- breadth-first act: phase 1 = all 12 exps ---- */                    \
    const float ei0 = fast_ex2(E0[0] * -L2E);                                   \
    const float ei1 = fast_ex2(E1[0] * -L2E);                                   \
    const float ei2 = fast_ex2(E2[0] * -L2E);                                   \
    const float ef0 = fast_ex2(E0[1] * -L2E);                                   \
    const float ef1 = fast_ex2(E1[1] * -L2E);                                   \
    const float ef2 = fast_ex2(E2[1] * -L2E);                                   \
    const float eg0 = fast_ex2(E0[2] *  L2E2);                                  \
    const float eg1 = fast_ex2(E1[2] *  L2E2);                                  \
    const float eg2 = fast_ex2(E2[2] *  L2E2);                                  \
    const float eo0 = fast_ex2(E0[3] * -L2E);                                   \
    const float eo1 = fast_ex2(E1[3] * -L2E);                                   \
    const float eo2 = fast_ex2(E2[3] * -L2E);                                   \
    /* ---- phase 2: denominators + R1 rcps + numerators ---- */                \
    const float Dn0 = 1.f + ef0;                                                \
    const float Dn1 = 1.f + ef1;                                                \
    const float Dn2 = 1.f + ef2;                                                \
    const float Pp0 = (1.f + ei0) * (eg0 + 1.f);                                \
    const float Pp1 = (1.f + ei1) * (eg1 + 1.f);                                \
    const float Pp2 = (1.f + ei2) * (eg2 + 1.f);                                \
    const float R10 = fast_rcp(Dn0 * Pp0);                                      \
    const float R11 = fast_rcp(Dn1 * Pp1);                                      \
    const float R12 = fast_rcp(Dn2 * Pp2);                                      \
    const float nm0 = fmaf(c0, Pp0, Dn0 * (eg0 - 1.f));                         \
    const float nm1 = fmaf(c1, Pp1, Dn1 * (eg1 - 1.f));                         \
    const float nm2 = fmaf(c2, Pp2, Dn2 * (eg2 - 1.f));                         \
    /* ---- phase 3: c' updates + es exps ---- */                               \
    c0 = nm0 * R10;                                                             \
    c1 = nm1 * R11;                                                             \
    c2 = nm2 * R12;                                                             \
    const float es0 = fast_ex2(__builtin_fabsf(c0) * -L2E2);                    \
    const float es1 = fast_ex2(__builtin_fabsf(c1) * -L2E2);                    \
    const float es2 = fast_ex2(__builtin_fabsf(c2) * -L2E2);                    \
    /* ---- phase 4: R2 rcps + h ---- */                                        \
    const float R20_ = fast_rcp((1.f + eo0) * (1.f + es0));                     \
    const float R21_ = fast_rcp((1.f + eo1) * (1.f + es1));                     \
    const float R22_ = fast_rcp((1.f + eo2) * (1.f + es2));                     \
    const float h0 = __builtin_copysignf((1.f - es0) * R20_, c0);               \
    const float h1 = __builtin_copysignf((1.f - es1) * R21_, c1);               \
    const float h2 = __builtin_copysignf((1.f - es2) * R22_, c2);               \
    /* partner (lane^8) via DPP; overflow pairs pre-packed at q3, 2 shfls */    \
    const float s0 = dpp_xor8(h0);                                              \
    const float s1 = dpp_xor8(h1);                                              \
    const float s2 = dpp_xor8(h2);                                              \
    const float Xa = __builtin_bit_cast(float,                                  \
        pk2(mhi ? h1 : h0, mhi ? h2 : h1));  /* q3lo:(u6,u7) q3hi:(u22,u23) */  \
    const float Xb = __builtin_bit_cast(float, pk2(h2, s0)); /* q3lo:(u14,u15)*/\
    const float rcv1 = __shfl(Xa, srcX, 64);                                    \
    const float rcv2 = __shfl(Xb, srcQ1, 64);                                   \
    if (q < 3) {                                                                \
      B.h2[0] = pk2(mhi ? s0 : h0, mhi ? s1 : h1);                              \
      B.h2[1] = pk2(mhi ? s2 : h2, mhi ? h0 : s0);                              \
      B.h2[2] = pk2(mhi ? h1 : s1, mhi ? h2 : s2);                              \
      B.h2[3] = __builtin_bit_cast(half2t, (q == 1) ? rcv2 : rcv1);             \
    } else {                                                                    \
      B.h2[0] = pk2(xsK[0], xsK[1]);                                            \
      B.h2[1] = pk2(xsK[2], xsK[3]);                                            \
      B.h2[2] = pk2(xsK[4], 1.0f);                                              \
      B.h2[3] = pk2(0.f, 0.f);                                                  \
    }                                                                           \
    { U16B fF; fF.f4 = faK;                                                     \
      accF = MFMA16(fF.h8, B.h8, accF); }                                       \
  }

// slot reloads (main loop only): fa via pointer + literal offset (in-bounds by
// construction: t <= 196 -> step t+4+K <= 203); xs keeps its uniform clamp.
#define RELD(K, faK, xsK)                                                       \
  faK = fap[(K)*64];                                                            \
  if (q == 3) {                                                                 \
    const int txi = (t + (K) + 5 < T_) ? t + (K) + 5 : T_ - 1;                  \
    const float* xq = xp + txi*I_;                                              \
    _Pragma("unroll")                                                           \
    for (int i = 0; i < I_; ++i) xsK[i] = xq[i];                                \
  }

__global__ __launch_bounds__(64)
void lstm_mfma(const float* __restrict__ x,
               const float* __restrict__ W_ih,
               const float* __restrict__ W_hh,
               const float* __restrict__ b_ih,
               const float* __restrict__ b_hh,
               const float* __restrict__ fc0_b,
               const float* __restrict__ out_w,
               const float* __restrict__ out_b,
               const float4t* __restrict__ fc0A,   // prepacked in d_ws
               float* __restrict__ out)
{
    __shared__ __align__(16) _Float16 actL[16*24];  // epilogue staging only

    const int lane = threadIdx.x;
    const int m = lane & 15;         // B col (batch, cols 8-15 duplicate 0-7)
    const int q = lane >> 4;         // quad
    const int mb = m & 7;            // batch sub-index
    const bool mhi = (m >= 8);       // upper half: owns unit tiles 3-5
    const int eb = blockIdx.x * 8 + mb;   // batch element

    // pull source lanes: Xa consumers q0 (48+mb) and q2 (56+mb); Xb: q1 (48+mb)
    const int srcX  = ((q == 2) ? 56 : 48) + mb;
    const int srcQ1 = 48 + mb;

    const float4t zf4 = {0.f, 0.f, 0.f, 0.f};

    // ---- gate A-fragments (identical to R20/R22) ----
    half8 Ag[6];
    #pragma unroll
    for (int T6 = 0; T6 < 6; ++T6) {
        const int u = unit_of(m >> 2, T6);
        const int srow = (m & 3) * H_ + u;       // torch gate-major row
        float wv[8];
        if (q < 3) {
            const float4t* pw = (const float4t*)(W_hh + srow*H_ + 8*q);
            float4t wa = pw[0], wb = pw[1];
            #pragma unroll
            for (int i = 0; i < 4; ++i) { wv[i] = wa[i]; wv[4+i] = wb[i]; }
        } else {
            #pragma unroll
            for (int i = 0; i < 8; ++i) wv[i] = 0.f;
            #pragma unroll
            for (int i = 0; i < I_; ++i) wv[i] = W_ih[srow*I_ + i];
            wv[5] = b_ih[srow] + b_hh[srow];
        }
        U16B tw;
        #pragma unroll
        for (int i = 0; i < 8; ++i) tw.h[i] = (_Float16)wv[i];
        Ag[T6] = tw.h8;
    }

    const float* xp = x + (size_t)eb * (T_*I_);

    // ---- initial B-frag [h=0 | x_0 | 1 | 0,0] ----
    U16B B;
    if (q == 3) {
        B.h2[0] = pk2(xp[0], xp[1]);
        B.h2[1] = pk2(xp[2], xp[3]);
        B.h2[2] = pk2(xp[4], 1.0f);
        B.h2[3] = pk2(0.f, 0.f);
    } else {
        B.f4 = zf4;
    }

    // ---- depth-4 prefetch ring, named slots ----
    float4t fa0 = fc0A[0*64 + lane];
    float4t fa1 = fc0A[1*64 + lane];
    float4t fa2 = fc0A[2*64 + lane];
    float4t fa3 = fc0A[3*64 + lane];
    const float4t* fap = fc0A + 4*64 + lane;    // slot base for step t+4
    float xs0[I_] = {0,0,0,0,0}, xs1[I_] = {0,0,0,0,0};
    float xs2[I_] = {0,0,0,0,0}, xs3[I_] = {0,0,0,0,0};
    if (q == 3) {
        #pragma unroll
        for (int i = 0; i < I_; ++i) {
            xs0[i] = xp[1*I_ + i];   // x(1) consumed at t=0
            xs1[i] = xp[2*I_ + i];
            xs2[i] = xp[3*I_ + i];
            xs3[i] = xp[4*I_ + i];
        }
    }

    // 3 cell states per lane: units unit_of(q, (mhi?3:0)+j), batch mb
    float c0 = 0.f, c1 = 0.f, c2 = 0.f;
    float4t accF = zf4;

    // ============ main loop: 50 x 4 steps (0..199), reloads in-bounds =======
    #pragma unroll 1
    for (int t = 0; t <= 196; t += 4) {
        POSC(fa0, xs0)  RELD(0, fa0, xs0)
        POSC(fa1, xs1)  RELD(1, fa1, xs1)
        POSC(fa2, xs2)  RELD(2, fa2, xs2)
        POSC(fa3, xs3)  RELD(3, fa3, xs3)
        fap += 4*64;
    }
    // ============ peel: steps 200-203, no reloads ===========================
    POSC(fa0, xs0)
    POSC(fa1, xs1)
    POSC(fa2, xs2)
    POSC(fa3, xs3)

    // ================= epilogue (R7/R8 structure; stores m<8 only) =========
    float av[4];
    #pragma unroll
    for (int r = 0; r < 4; ++r) {
        const int l = 4*q + r;
        const float fb = (l < L_) ? fc0_b[l] : 0.f;
        const float v = accF[r] + fb;
        av[r] = (l < L_) ? fmaxf(v, 0.f) : 0.f;
    }
    *(half2t*)(&actL[m*24 + 4*q])     = pk2(av[0], av[1]);
    *(half2t*)(&actL[m*24 + 4*q + 2]) = pk2(av[2], av[3]);
    __builtin_amdgcn_wave_barrier();

    U16B Ba;
    if (q < 2) Ba.f4 = *(const float4t*)(&actL[m*24 + q*8]);
    else       Ba.f4 = zf4;            // k>=16 unused (out_w A-frag zero there)

    for (int Tt = 0; Tt < 39; ++Tt) {
        const int row = 16*Tt + m;
        float w0=0.f,w1=0.f,w2=0.f,w3=0.f,w4=0.f,w5=0.f,w6=0.f,w7=0.f;
        if (row < O_ && q < 2) {
            const float2* p2 = (const float2*)(out_w + row*L_);
            if (q == 0) {
                float2 a = p2[0], b = p2[1], cc = p2[2], dd = p2[3];
                w0=a.x; w1=a.y; w2=b.x; w3=b.y; w4=cc.x; w5=cc.y; w6=dd.x; w7=dd.y;
            } else {
                float2 a = p2[4];
                w0=a.x; w1=a.y;
            }
        }
        U16B Aw;
        Aw.h2[0] = pk2(w0,w1); Aw.h2[1] = pk2(w2,w3);
        Aw.h2[2] = pk2(w4,w5); Aw.h2[3] = pk2(w6,w7);

        float4t dd = MFMA16(Aw.h8, Ba.h8, zf4);

        const int ob = 16*Tt + 4*q;
        if (ob < O_ && m < 8) {
            const float4t bias = *(const float4t*)(out_b + ob);
            #pragma unroll
            for (int r = 0; r < 4; ++r) dd[r] += bias[r];
            *(float4t*)(out + (size_t)eb*O_ + ob) = dd;
        }
    }
}

extern "C" void kernel_launch(void* const* d_in, const int* in_sizes, int n_in,
                              void* d_out, int out_size, void* d_ws, size_t ws_size,
                              hipStream_t stream)
{
    const float* x     = (const float*)d_in[0];
    const float* W_ih  = (const float*)d_in[1];
    const float* W_hh  = (const float*)d_in[2];
    const float* b_ih  = (const float*)d_in[3];
    const float* b_hh  = (const float*)d_in[4];
    const float* fc0_w = (const float*)d_in[5];
    const float* fc0_b = (const float*)d_in[6];
    const float* out_w = (const float*)d_in[7];
    const float* out_b = (const float*)d_in[8];
    float* out = (float*)d_out;
    (void)ws_size;

    pack_fc0<<<dim3(T_), dim3(64), 0, stream>>>(fc0_w, (float4t*)d_ws);
    lstm_mfma<<<dim3(Bsz/8), dim3(64), 0, stream>>>(
        x, W_ih, W_hh, b_ih, b_hh, fc0_b, out_w, out_b,
        (const float4t*)d_ws, out);
}